// Round 5
// baseline (493.630 us; speedup 1.0000x reference)
//
#include <hip/hip_runtime.h>
#include <hip/hip_bf16.h>
#include <stdint.h>

using bf16x8 = __attribute__((ext_vector_type(8))) __bf16;
using bf16x4 = __attribute__((ext_vector_type(4))) __bf16;
using f32x4  = __attribute__((ext_vector_type(4))) float;

typedef const uint32_t __attribute__((address_space(1)))* gas_ptr;
typedef uint32_t __attribute__((address_space(3)))* las_ptr;

__device__ __forceinline__ void load_lds16(const void* g, void* l) {
    __builtin_amdgcn_global_load_lds((gas_ptr)g, (las_ptr)l, 16, 0, 0);
}

// cprelu post-normalization constants (PRELU_INIT = 0.25)
#define PM  0.29920671030107454f
#define PIS 1.5046096f
#define RHALF 0.70710678118654752f

// ---------------------------------------------------------------- k_conv
// Fused: conn fp32 -> bf16 (row-private, read-all-then-write so in-place is
// safe) + per-row max + tie-index collection (exact fp32 equality, cap 16)
// + (blocks 0..31) weight pad/convert to bf16 (former k_prep).
__global__ __launch_bounds__(256) void k_conv(const float* __restrict__ conn,
                                              __bf16* __restrict__ cb,
                                              size_t rowstride,
                                              int* __restrict__ cnt,
                                              int* __restrict__ idx,
                                              const float* __restrict__ w1,
                                              const float* __restrict__ w2,
                                              const float* __restrict__ wm,
                                              const float* __restrict__ wsw,
                                              __bf16* __restrict__ W1p,
                                              __bf16* __restrict__ W2p,
                                              __bf16* __restrict__ WMp,
                                              __bf16* __restrict__ WSp)
{
    const int o = blockIdx.x;
    const int t = threadIdx.x;
    const float* row = conn + (size_t)o * 8192;
    float4 v[8];
    float m = -1e30f;
#pragma unroll
    for (int q = 0; q < 8; q++) {
        v[q] = *(const float4*)(row + (size_t)(q * 256 + t) * 4);
        m = fmaxf(m, fmaxf(fmaxf(v[q].x, v[q].y), fmaxf(v[q].z, v[q].w)));
    }
    __syncthreads();   // all reads drained before in-place overwrite
    __bf16* drow = cb + (size_t)o * rowstride;
#pragma unroll
    for (int q = 0; q < 8; q++) {
        bf16x4 w;
        w[0] = (__bf16)v[q].x; w[1] = (__bf16)v[q].y;
        w[2] = (__bf16)v[q].z; w[3] = (__bf16)v[q].w;
        *(bf16x4*)(drow + (size_t)(q * 256 + t) * 4) = w;
    }
#pragma unroll
    for (int off = 32; off > 0; off >>= 1) m = fmaxf(m, __shfl_down(m, off, 64));
    __shared__ float wmax[4];
    __shared__ int scnt;
    if ((t & 63) == 0) wmax[t >> 6] = m;
    if (t == 0) scnt = 0;
    __syncthreads();
    const float rmax = fmaxf(fmaxf(wmax[0], wmax[1]), fmaxf(wmax[2], wmax[3]));
#pragma unroll
    for (int q = 0; q < 8; q++) {
        float vv[4] = {v[q].x, v[q].y, v[q].z, v[q].w};
#pragma unroll
        for (int e = 0; e < 4; e++) {
            if (vv[e] >= rmax) {
                int p = atomicAdd(&scnt, 1);
                if (p < 16) idx[o * 16 + p] = (q * 256 + t) * 4 + e;
            }
        }
    }
    __syncthreads();
    if (t == 0) cnt[o] = scnt < 16 ? scnt : 16;

    // former k_prep, folded into the first 32 blocks
    if (o < 32) {
        const int id = o * 256 + t;
        const int stride = 32 * 256;
        for (int i = id; i < 96 * 64; i += stride) {
            int oc = i >> 6, ic = i & 63;
            W1p[i] = (__bf16)((oc < 83) ? w1[oc * 64 + ic] : 0.f);
        }
        for (int i = id; i < 112 * 96; i += stride) {
            int oc = i / 96, ic = i % 96;
            W2p[i] = (__bf16)((oc < 102 && ic < 83) ? w2[oc * 83 + ic] : 0.f);
        }
        for (int i = id; i < 128 * 128; i += stride) {
            int oc = i >> 7, ic = i & 127;
            WMp[i] = (__bf16)((ic < 102) ? wm[oc * 102 + ic] : 0.f);
        }
        for (int i = id; i < 128 * 64; i += stride) {
            WSp[i] = (__bf16)wsw[i];
        }
    }
}

// ---------------------------------------------------------------- k_chain
template<int KS>
__device__ __forceinline__ f32x4 mfma_tile(const __bf16* __restrict__ W, int wstride, int mt,
                                           const __bf16* B, int bstride, int nt, int lane)
{
    f32x4 acc = {0.f, 0.f, 0.f, 0.f};
    const int l15 = lane & 15;
    const int kg  = (lane >> 4) << 3;
    const __bf16* wp = W + (mt * 16 + l15) * wstride + kg;
    const __bf16* bp = B + (nt * 16 + l15) * bstride + kg;
#pragma unroll
    for (int ks = 0; ks < KS; ks++) {
        bf16x8 av = *(const bf16x8*)(wp + ks * 32);
        bf16x8 bv = *(const bf16x8*)(bp + ks * 32);
        acc = __builtin_amdgcn_mfma_f32_16x16x32_bf16(av, bv, acc, 0, 0, 0);
    }
    return acc;
}

__global__ __launch_bounds__(256) void k_chain(
    const float* __restrict__ x,
    const float* __restrict__ b1, const float* __restrict__ p1,
    const float* __restrict__ b2, const float* __restrict__ p2,
    const float* __restrict__ bm, const float* __restrict__ bs,
    const __bf16* __restrict__ W1p, const __bf16* __restrict__ W2p,
    const __bf16* __restrict__ WMp, const __bf16* __restrict__ WSp,
    __bf16* __restrict__ h3, __bf16* __restrict__ s_t)
{
    __shared__ __bf16 buf0[64 * 136];   // Xt (stride 72) then H2t (stride 136)
    __shared__ __bf16 un[128 * 72];     // OutS(132) / H1t(104) / OutT(72)
    __shared__ float  bl[672];
    __bf16* OutS = un;                  // 64 x 132 (pad vs 16-way write conflict)
    __bf16* H1t  = un;                  // 64 x 104
    __bf16* OutT = un;                  // 128 x 72
    float* b1l = bl;       float* p1l = bl + 96;
    float* b2l = bl + 192; float* p2l = bl + 304;
    float* bml = bl + 416; float* bsl = bl + 544;

    const int t = threadIdx.x, lane = t & 63, wid = t >> 6;
    const int b = blockIdx.y;
    const int p0 = blockIdx.x * 64;

    for (int i = t; i < 96; i += 256)  { b1l[i] = (i < 83)  ? b1[i] : 0.f; p1l[i] = (i < 83)  ? p1[i] : 0.f; }
    for (int i = t; i < 112; i += 256) { b2l[i] = (i < 102) ? b2[i] : 0.f; p2l[i] = (i < 102) ? p2[i] : 0.f; }
    for (int i = t; i < 128; i += 256) { bml[i] = bm[i]; bsl[i] = bs[i]; }

    {
        const int p = t & 63;
        const int cg = t >> 6;     // 0..3
#pragma unroll 4
        for (int it = 0; it < 16; it++) {
            int c = it * 4 + cg;
            buf0[p * 72 + c] = (__bf16)x[((size_t)b * 64 + c) * 8192 + p0 + p];
        }
    }
    __syncthreads();

    const int quad4 = (lane >> 4) << 2;
    const int l15 = lane & 15;

    // shortcut S = WS*X + bs  (8 mt x 4 nt) -> OutS[pos][c] in LDS
    for (int tt = wid; tt < 32; tt += 4) {
        int mt = tt >> 2, nt = tt & 3;
        f32x4 a = mfma_tile<2>(WSp, 64, mt, buf0, 72, nt, lane);
        int ocb = mt * 16 + quad4;
        int pos = nt * 16 + l15;
        bf16x4 ov;
#pragma unroll
        for (int r = 0; r < 4; r++) ov[r] = (__bf16)(a[r] + bsl[ocb + r]);
        *(bf16x4*)(&OutS[pos * 132 + ocb]) = ov;
    }
    __syncthreads();
    // coalesced OutS -> s_t (16 KB contiguous: [pos 0..63][c 0..127])
    {
        __bf16* dst = s_t + ((size_t)b * 8192 + p0) * 128;
#pragma unroll
        for (int it = 0; it < 4; it++) {
            int lin = it * 256 + t;            // 0..1023
            int pos = lin >> 4, c8 = (lin & 15) * 8;
            bf16x8 v = *(const bf16x8*)(OutS + pos * 132 + c8);
            *(bf16x8*)(dst + lin * 8) = v;
        }
    }
    __syncthreads();

    // H1 = cprelu(W1*X + b1)  (6 mt x 4 nt) -> H1t (overwrites OutS region)
    for (int tt = wid; tt < 24; tt += 4) {
        int mt = tt >> 2, nt = tt & 3;
        f32x4 a = mfma_tile<2>(W1p, 64, mt, buf0, 72, nt, lane);
        int ocb = mt * 16 + quad4;
        int pos = nt * 16 + l15;
        bf16x4 ov;
#pragma unroll
        for (int r = 0; r < 4; r++) {
            float v = a[r] + b1l[ocb + r];
            v = (v >= 0.f) ? v : v * p1l[ocb + r];
            ov[r] = (__bf16)((v - PM) * PIS);
        }
        *(bf16x4*)(&H1t[pos * 104 + ocb]) = ov;
    }
    __syncthreads();

    // H2 = cprelu(W2*H1 + b2)  (7 mt x 4 nt), into buf0 (Xt dead)
    for (int tt = wid; tt < 28; tt += 4) {
        int mt = tt >> 2, nt = tt & 3;
        f32x4 a = mfma_tile<3>(W2p, 96, mt, H1t, 104, nt, lane);
        int ocb = mt * 16 + quad4;
        int pos = nt * 16 + l15;
        bf16x4 ov;
#pragma unroll
        for (int r = 0; r < 4; r++) {
            float v = a[r] + b2l[ocb + r];
            v = (v >= 0.f) ? v : v * p2l[ocb + r];
            ov[r] = (__bf16)((v - PM) * PIS);
        }
        *(bf16x4*)(&buf0[pos * 136 + ocb]) = ov;
    }
    // zero H2 pad channels 112..127
    for (int i = t; i < 64 * 16; i += 256) {
        int pos = i >> 4, c = 112 + (i & 15);
        buf0[pos * 136 + c] = (__bf16)0.f;
    }
    __syncthreads();   // also: H1t reads done before OutT overwrites region

    // H3 = WM*H2 + bm  (8 mt x 4 nt) -> OutT[ch][pos] in LDS
    for (int tt = wid; tt < 32; tt += 4) {
        int mt = tt >> 2, nt = tt & 3;
        f32x4 a = mfma_tile<4>(WMp, 128, mt, buf0, 136, nt, lane);
        int ocb = mt * 16 + quad4;
        int pos = nt * 16 + l15;
#pragma unroll
        for (int r = 0; r < 4; r++)
            OutT[(ocb + r) * 72 + pos] = (__bf16)(a[r] + bml[ocb + r]);
    }
    __syncthreads();

    // coalesced OutT -> h3 (bf16x8 per lane, 128B per channel row)
#pragma unroll
    for (int it = 0; it < 4; it++) {
        int lin = it * 256 + t;       // 0..1023
        int ch = lin >> 3, pc = lin & 7;
        bf16x8 v = *(const bf16x8*)(OutT + ch * 72 + pc * 8);
        *(bf16x8*)(h3 + ((size_t)b * 128 + ch) * 8192 + p0 + pc * 8) = v;
    }
}

// ---------------------------------------------------------------- k_gemm
// C[2048,4096] = A[2048,8192](bf16) x B[4096,bstride](bf16, N x K rows)
// 128x128 tile, BK=64 (32KB LDS), split-K (up to 4) via blockIdx.z.
// XOR swizzle: 16B chunk (row, c) of a 64-elem row stored at c ^ (row & 7).
__global__ __launch_bounds__(256, 4) void k_gemm(const __bf16* __restrict__ A,
                                                 const __bf16* __restrict__ B,
                                                 size_t bstride,
                                                 float* __restrict__ C0,
                                                 float* __restrict__ P1,
                                                 float* __restrict__ P2,
                                                 float* __restrict__ P3,
                                                 int KH)
{
    __shared__ __bf16 la[128 * 64];
    __shared__ __bf16 lb[128 * 64];
    const int t = threadIdx.x;
    const int lane = t & 63;
    const int wid = t >> 6;
    const int tM = blockIdx.y * 128;
    const int tN = blockIdx.x * 128;
    const int kz = blockIdx.z;
    const int k0 = kz * KH;
    float* __restrict__ C = C0;
    if (kz == 1) C = P1; else if (kz == 2) C = P2; else if (kz == 3) C = P3;
    const int wm2 = (wid & 1) * 64;
    const int wn2 = (wid >> 1) * 64;

    f32x4 acc[4][4];
    const f32x4 zero = {0.f, 0.f, 0.f, 0.f};
#pragma unroll
    for (int i = 0; i < 4; i++)
#pragma unroll
        for (int j = 0; j < 4; j++) acc[i][j] = zero;

    // staging: 4 issues per matrix; issue i covers rows i*32..i*32+31
    const int tr = t >> 3;                    // 0..31
    const int sc = (t & 7) ^ (tr & 7);        // swizzled global chunk
    const __bf16* pA[4];
    const __bf16* pB[4];
#pragma unroll
    for (int i = 0; i < 4; i++) {
        pA[i] = A + (size_t)(tM + i * 32 + tr) * 8192 + k0 + sc * 8;
        pB[i] = B + (size_t)(tN + i * 32 + tr) * bstride + k0 + sc * 8;
    }

    const int l15 = lane & 15;
    const int q = lane >> 4;
    int aoff[4], boff[4];
#pragma unroll
    for (int i = 0; i < 4; i++) {
        int row = wm2 + i * 16 + l15;
        aoff[i] = row * 64 + ((q ^ (row & 7)) * 8);
    }
#pragma unroll
    for (int j = 0; j < 4; j++) {
        int row = wn2 + j * 16 + l15;
        boff[j] = row * 64 + ((q ^ (row & 7)) * 8);
    }

    const int iters = KH >> 6;
    for (int it = 0; it < iters; it++) {
#pragma unroll
        for (int i = 0; i < 4; i++) load_lds16(pA[i], la + (i * 256 + t) * 8);
#pragma unroll
        for (int i = 0; i < 4; i++) load_lds16(pB[i], lb + (i * 256 + t) * 8);
#pragma unroll
        for (int i = 0; i < 4; i++) { pA[i] += 64; pB[i] += 64; }
        __syncthreads();
#pragma unroll
        for (int ks = 0; ks < 2; ks++) {
            bf16x8 af[4], bfr[4];
#pragma unroll
            for (int i = 0; i < 4; i++) af[i]  = *(const bf16x8*)(la + (aoff[i] ^ (ks << 5)));
#pragma unroll
            for (int j = 0; j < 4; j++) bfr[j] = *(const bf16x8*)(lb + (boff[j] ^ (ks << 5)));
#pragma unroll
            for (int i = 0; i < 4; i++)
#pragma unroll
                for (int j = 0; j < 4; j++)
                    acc[i][j] = __builtin_amdgcn_mfma_f32_16x16x32_bf16(af[i], bfr[j], acc[i][j], 0, 0, 0);
        }
        __syncthreads();
    }

    const int quad4 = (lane >> 4) * 4;
#pragma unroll
    for (int i = 0; i < 4; i++) {
        int gm = tM + wm2 + i * 16 + quad4;
#pragma unroll
        for (int j = 0; j < 4; j++) {
            int gn = tN + wn2 + j * 16 + l15;
#pragma unroll
            for (int r = 0; r < 4; r++)
                C[(size_t)(gm + r) * 4096 + gn] = acc[i][j][r];
        }
    }
}

// ---------------------------------------------------------------- k_combine
// out = RHALF*pooled_shortcut + RHALF*cprelu(sum of partials, p3)
__global__ __launch_bounds__(256) void k_combine(float* __restrict__ out,
                                                 const float* __restrict__ P1,
                                                 const float* __restrict__ P2,
                                                 const float* __restrict__ P3,
                                                 int ns,
                                                 const __bf16* __restrict__ s_t,
                                                 const int* __restrict__ idx,
                                                 const int* __restrict__ cnt,
                                                 const float* __restrict__ p3)
{
    __shared__ float sp[64][133];
    const int b = blockIdx.y;
    const int o0 = blockIdx.x * 64;
    const int t = threadIdx.x;

    // phase 1: gather pooled shortcut rows into LDS
    {
        const int ol = t >> 2;
        const int part = t & 3;
        const int o = o0 + ol;
        const int n = cnt[o];
        float acc[32];
#pragma unroll
        for (int j = 0; j < 32; j++) acc[j] = 0.f;
        for (int k = 0; k < n; k++) {
            const int i = idx[o * 16 + k];
            const __bf16* row = s_t + ((size_t)b * 8192 + i) * 128 + part * 32;
#pragma unroll
            for (int j = 0; j < 32; j += 8) {
                bf16x8 v = *(const bf16x8*)(row + j);
#pragma unroll
                for (int u = 0; u < 8; u++) acc[j + u] += (float)v[u];
            }
        }
#pragma unroll
        for (int j = 0; j < 32; j++) sp[ol][part * 32 + j] = acc[j];
    }
    __syncthreads();

    // phase 2: float4-vectorized sum of partials + cprelu + mix
    const int ol4 = (t & 15) * 4;
    const int cbase = t >> 4;            // 0..15
#pragma unroll
    for (int cc = 0; cc < 8; cc++) {
        const int c = cc * 16 + cbase;
        const size_t oi = ((size_t)b * 128 + c) * 4096 + o0 + ol4;
        float4 v = *(const float4*)(out + oi);
        if (ns >= 2) {
            float4 a = *(const float4*)(P1 + oi);
            v.x += a.x; v.y += a.y; v.z += a.z; v.w += a.w;
        }
        if (ns >= 4) {
            float4 a2 = *(const float4*)(P2 + oi);
            float4 a3 = *(const float4*)(P3 + oi);
            v.x += a2.x + a3.x; v.y += a2.y + a3.y;
            v.z += a2.z + a3.z; v.w += a2.w + a3.w;
        }
        const float pw = p3[c];
        float4 r;
        float vv[4] = {v.x, v.y, v.z, v.w};
        float rr[4];
#pragma unroll
        for (int e = 0; e < 4; e++) {
            float y = (vv[e] >= 0.f) ? vv[e] : vv[e] * pw;
            y = (y - PM) * PIS;
            rr[e] = sp[ol4 + e][c] * RHALF + y * RHALF;
        }
        r.x = rr[0]; r.y = rr[1]; r.z = rr[2]; r.w = rr[3];
        *(float4*)(out + oi) = r;
    }
}

// ---------------------------------------------------------------- launch
extern "C" void kernel_launch(void* const* d_in, const int* in_sizes, int n_in,
                              void* d_out, int out_size, void* d_ws, size_t ws_size,
                              hipStream_t stream) {
    (void)in_sizes; (void)n_in; (void)out_size;
    const float* x    = (const float*)d_in[0];
    const float* conn = (const float*)d_in[1];
    const float* w1   = (const float*)d_in[2];
    const float* b1   = (const float*)d_in[3];
    const float* p1   = (const float*)d_in[4];
    const float* w2   = (const float*)d_in[5];
    const float* b2   = (const float*)d_in[6];
    const float* p2   = (const float*)d_in[7];
    const float* wm   = (const float*)d_in[8];
    const float* bm   = (const float*)d_in[9];
    const float* p3   = (const float*)d_in[10];
    const float* wsw  = (const float*)d_in[11];
    const float* bs   = (const float*)d_in[12];
    float* out = (float*)d_out;

    char* ws = (char*)d_ws;
    __bf16* h3  = (__bf16*)(ws);                          // 33,554,432 B
    __bf16* s_t = (__bf16*)(ws + 33554432);               // 33,554,432 B
    __bf16* W1p = (__bf16*)(ws + 67108864);               // 12,288
    __bf16* W2p = (__bf16*)(ws + 67108864 + 12288);       // 21,504
    __bf16* WMp = (__bf16*)(ws + 67108864 + 33792);       // 32,768
    __bf16* WSp = (__bf16*)(ws + 67108864 + 66560);       // 16,384
    int* idx = (int*)(ws + 67108864 + 82944);             // 262,144
    int* cnt = (int*)(ws + 67108864 + 82944 + 262144);    // 16,384
    const size_t pbase = 67108864 + 82944 + 262144 + 16384;   // 67,470,336
    const size_t psz = 33554432;
    const size_t connb_sz = (size_t)4096 * 8192 * 2;

    int nsplit; bool conn_ws;
    if      (ws_size >= pbase + 3 * psz + connb_sz) { nsplit = 4; conn_ws = true;  }
    else if (ws_size >= pbase + 3 * psz)            { nsplit = 4; conn_ws = false; }
    else if (ws_size >= pbase + 1 * psz + connb_sz) { nsplit = 2; conn_ws = true;  }
    else if (ws_size >= pbase + 1 * psz)            { nsplit = 2; conn_ws = false; }
    else { nsplit = 1; conn_ws = (ws_size >= pbase + connb_sz); }

    float* Pk1 = (float*)(ws + pbase);
    float* Pk2 = (float*)(ws + pbase + psz);
    float* Pk3 = (float*)(ws + pbase + 2 * psz);

    __bf16* connb;
    size_t  cstride;
    if (conn_ws) {
        connb = (__bf16*)(ws + pbase + (size_t)(nsplit - 1) * psz);
        cstride = 8192;
    } else {
        connb = (__bf16*)const_cast<float*>(conn);
        cstride = 16384;   // bf16 row packed into first half of its fp32 row
    }
    const int KH = 8192 / nsplit;

    k_conv<<<4096, 256, 0, stream>>>(conn, connb, cstride, cnt, idx,
                                     w1, w2, wm, wsw, W1p, W2p, WMp, WSp);
    k_chain<<<dim3(8192 / 64, 16), 256, 0, stream>>>(x, b1, p1, b2, p2, bm, bs,
                                                     W1p, W2p, WMp, WSp, h3, s_t);
    k_gemm<<<dim3(4096 / 128, 2048 / 128, nsplit), 256, 0, stream>>>(h3, connb, cstride,
                                                                     out, Pk1, Pk2, Pk3, KH);
    k_combine<<<dim3(4096 / 64, 16), 256, 0, stream>>>(out, Pk1, Pk2, Pk3, nsplit,
                                                       s_t, idx, cnt, p3);
}